// Round 6
// baseline (357.828 us; speedup 1.0000x reference)
//
#include <hip/hip_runtime.h>

#define D 128
#define N_CLS 40

// ---------------------------------------------------------------------------
// bf16 helpers (RNE)
// ---------------------------------------------------------------------------
__device__ __forceinline__ unsigned f2bf(float f) {
  unsigned u = __builtin_bit_cast(unsigned, f);
  u += 0x7fffu + ((u >> 16) & 1u);
  return u >> 16;
}
__device__ __forceinline__ float bf_lo(unsigned u) {
  return __builtin_bit_cast(float, u << 16);
}
__device__ __forceinline__ float bf_hi(unsigned u) {
  return __builtin_bit_cast(float, u & 0xffff0000u);
}

// ---------------------------------------------------------------------------
// CSR build step 1: counts[dst[e]]++
// ---------------------------------------------------------------------------
__global__ __launch_bounds__(256) void count_kernel(
    const int* __restrict__ dst, int* __restrict__ counts, int n_edges) {
  int e = blockIdx.x * 256 + threadIdx.x;
  if (e < n_edges) atomicAdd(&counts[dst[e]], 1);
}

// 3-phase device-wide exclusive scan over counts[n] (n % 4 == 0).
__global__ __launch_bounds__(256) void scan_partA(
    const int* __restrict__ counts, int* __restrict__ partials, int n4) {
  __shared__ int sh[256];
  const int tid = threadIdx.x;
  const int g = blockIdx.x * 256 + tid;
  int s = 0;
  if (g < n4) {
    const int4 c = reinterpret_cast<const int4*>(counts)[g];
    s = c.x + c.y + c.z + c.w;
  }
  sh[tid] = s;
  __syncthreads();
  for (int off = 128; off > 0; off >>= 1) {
    if (tid < off) sh[tid] += sh[tid + off];
    __syncthreads();
  }
  if (tid == 0) partials[blockIdx.x] = sh[0];
}

__global__ __launch_bounds__(64) void scan_partB(
    int* __restrict__ partials, int* __restrict__ row_start, int nP,
    int n, int n_edges) {
  const int lane = threadIdx.x;
  int v = (lane < nP) ? partials[lane] : 0;
  int x = v;
  for (int off = 1; off < 64; off <<= 1) {
    int y = __shfl_up(x, off, 64);
    if (lane >= off) x += y;
  }
  if (lane < nP) partials[lane] = x - v;
  if (lane == 0) row_start[n] = n_edges;
}

__global__ __launch_bounds__(256) void scan_partC(
    int* __restrict__ counts, const int* __restrict__ partials,
    int* __restrict__ row_start, int n4) {
  __shared__ int sh[256];
  const int tid = threadIdx.x;
  const int g = blockIdx.x * 256 + tid;
  int4 c = make_int4(0, 0, 0, 0);
  if (g < n4) c = reinterpret_cast<const int4*>(counts)[g];
  const int s0 = c.x;
  const int s1 = s0 + c.y;
  const int s2 = s1 + c.z;
  const int s3 = s2 + c.w;
  sh[tid] = s3;
  __syncthreads();
  for (int off = 1; off < 256; off <<= 1) {
    int y = (tid >= off) ? sh[tid - off] : 0;
    __syncthreads();
    sh[tid] += y;
    __syncthreads();
  }
  if (g < n4) {
    const int base = partials[blockIdx.x] + sh[tid] - s3;
    const int4 rs = make_int4(base, base + s0, base + s1, base + s2);
    reinterpret_cast<int4*>(row_start)[g] = rs;
    reinterpret_cast<int4*>(counts)[g] = rs;
  }
}

__global__ __launch_bounds__(256) void fill_kernel(
    const int* __restrict__ src, const int* __restrict__ dst,
    int* __restrict__ cursor, int* __restrict__ col_idx, int n_edges) {
  int e = blockIdx.x * 256 + threadIdx.x;
  if (e < n_edges) {
    int p = atomicAdd(&cursor[dst[e]], 1);
    col_idx[p] = src[e];
  }
}

// ---------------------------------------------------------------------------
// Merged converter. x -> bf16 in SLICED layout: slice s holds cols [32s,32s+32)
// of every row, contiguous: xb[((s*M)+row)*32 + (col&31)].
// Blocks [0,nxb): x.  Blocks [nxb, ...): W0/W1/W2 (W2 padded to 48 rows).
// ---------------------------------------------------------------------------
__global__ __launch_bounds__(256) void convert_all(
    const float4* __restrict__ x4, unsigned* __restrict__ xb, int n4, int nxb,
    int M,
    const float* __restrict__ W0, const float* __restrict__ W1,
    const float* __restrict__ W2, unsigned short* __restrict__ W0b,
    unsigned short* __restrict__ W1b, unsigned short* __restrict__ W2b) {
  if ((int)blockIdx.x < nxb) {
    int i = blockIdx.x * 256 + threadIdx.x;
    if (i < n4) {
      float4 v = x4[i];
      int row = i >> 5;            // 32 float4 per row
      int q = i & 31;              // float4 index in row; col0 = q*4
      int slice = q >> 3;          // col0>>5
      int dw = (q & 7) * 2;        // dword offset within 16-dword slice row
      unsigned* o = xb + ((size_t)slice * M + row) * 16 + dw;
      o[0] = f2bf(v.x) | (f2bf(v.y) << 16);
      o[1] = f2bf(v.z) | (f2bf(v.w) << 16);
    }
  } else {
    int idx = (blockIdx.x - nxb) * 256 + threadIdx.x;
    const int n0 = 128 * 128, n1 = 128 * 128, n2 = 48 * 128;
    if (idx < n0) {
      W0b[idx] = (unsigned short)f2bf(W0[idx]);
    } else if (idx < n0 + n1) {
      int i = idx - n0;
      W1b[i] = (unsigned short)f2bf(W1[i]);
    } else if (idx < n0 + n1 + n2) {
      int i = idx - n0 - n1;
      int r = i >> 7;
      W2b[i] = (r < N_CLS) ? (unsigned short)f2bf(W2[i]) : (unsigned short)0;
    }
  }
}

// ---------------------------------------------------------------------------
// Sliced gather: out[n, slice p] = h[n,p] + sum_j h[col_idx[j], p]
// pass p = blockIdx & 3  ->  on round-robin XCD mapping, each XCD touches one
// 3.2 MB slice (fits 4 MB L2). 16 lanes per node (64 B = 1 line per neighbor),
// 4 nodes per wave, 16 nodes per block-quarter. M must be %16 (50000 ok).
// ---------------------------------------------------------------------------
__global__ __launch_bounds__(256) void gather_sliced(
    const unsigned* __restrict__ H, const int* __restrict__ row_start,
    const int* __restrict__ col_idx, unsigned* __restrict__ out, int M) {
  const int pass = blockIdx.x & 3;
  const int node = (blockIdx.x >> 2) * 16 + (threadIdx.x >> 4);
  const int l = threadIdx.x & 15;
  if (node >= M) return;
  const unsigned* Hp = H + (size_t)pass * M * 16;  // 16 dwords per node
  unsigned su = Hp[(size_t)node * 16 + l];
  float ax = bf_lo(su), ay = bf_hi(su);
  float bx = 0.f, by = 0.f, cx = 0.f, cy = 0.f, dx = 0.f, dy = 0.f;
  int s = row_start[node];
  int e = row_start[node + 1];
  int j = s;
  for (; j + 3 < e; j += 4) {
    int u0 = __builtin_nontemporal_load(col_idx + j + 0);
    int u1 = __builtin_nontemporal_load(col_idx + j + 1);
    int u2 = __builtin_nontemporal_load(col_idx + j + 2);
    int u3 = __builtin_nontemporal_load(col_idx + j + 3);
    unsigned v0 = Hp[(size_t)u0 * 16 + l];
    unsigned v1 = Hp[(size_t)u1 * 16 + l];
    unsigned v2 = Hp[(size_t)u2 * 16 + l];
    unsigned v3 = Hp[(size_t)u3 * 16 + l];
    ax += bf_lo(v0); ay += bf_hi(v0);
    bx += bf_lo(v1); by += bf_hi(v1);
    cx += bf_lo(v2); cy += bf_hi(v2);
    dx += bf_lo(v3); dy += bf_hi(v3);
  }
  for (; j < e; ++j) {
    int u = __builtin_nontemporal_load(col_idx + j);
    unsigned v = Hp[(size_t)u * 16 + l];
    ax += bf_lo(v); ay += bf_hi(v);
  }
  ax += bx + cx + dx;
  ay += by + cy + dy;
  out[(size_t)pass * M * 16 + (size_t)node * 16 + l] = f2bf(ax) | (f2bf(ay) << 16);
}

// ---------------------------------------------------------------------------
// MFMA GEMM: out[M, ncols] = act(A_sliced[M,128] @ B[NT*16,128]^T + bias)
// A in sliced layout (slice ks = cols [32ks,32ks+32), 64 B/node/slice).
// Block = 256 thr = 4 waves, 64 rows/block; wave w: rows blk*64+w*16..+15.
// A-frag ks: lane(r16,quad) reads 16 B at slice ks, node m_base+r16, dword quad*4.
// C/D: col = lane&15, row = quad*4 + reg.
// OUTSLICED: write bf16 to sliced layout; else fp32 row-major [M,ncols].
// ---------------------------------------------------------------------------
typedef __attribute__((ext_vector_type(8))) short bf16x8;
typedef __attribute__((ext_vector_type(4))) float f32x4;

template <int NT, bool RELU, bool OUTSLICED>
__global__ __launch_bounds__(256) void gemm_mfma(
    const unsigned short* __restrict__ A, const unsigned short* __restrict__ B,
    const float* __restrict__ bias, void* __restrict__ out, int M, int ncols) {
  const int tid = threadIdx.x;
  const int wv = tid >> 6;
  const int lane = tid & 63;
  const int m_base = blockIdx.x * 64 + wv * 16;
  const int r16 = lane & 15;
  const int quad = lane >> 4;
  const int arow = min(m_base + r16, M - 1);  // clamp; padding rows harmless

  bf16x8 af[4];
#pragma unroll
  for (int ks = 0; ks < 4; ++ks)
    af[ks] = *reinterpret_cast<const bf16x8*>(
        (const short*)A + ((size_t)ks * M + arow) * 32 + quad * 8);

  f32x4 acc[NT];
#pragma unroll
  for (int nt = 0; nt < NT; ++nt) {
    acc[nt] = (f32x4){0.f, 0.f, 0.f, 0.f};
    const short* Bp = (const short*)B + (size_t)(nt * 16 + r16) * D + quad * 8;
#pragma unroll
    for (int ks = 0; ks < 4; ++ks) {
      bf16x8 bf = *reinterpret_cast<const bf16x8*>(Bp + ks * 32);
      acc[nt] = __builtin_amdgcn_mfma_f32_16x16x32_bf16(af[ks], bf, acc[nt], 0, 0, 0);
    }
  }

  const int orow = m_base + quad * 4;
#pragma unroll
  for (int nt = 0; nt < NT; ++nt) {
    int col = nt * 16 + r16;
    float bv = (col < ncols) ? bias[col] : 0.f;
#pragma unroll
    for (int r = 0; r < 4; ++r) {
      int grow = orow + r;
      if (grow < M && col < ncols) {
        float v = acc[nt][r] + bv;
        if (RELU) v = fmaxf(v, 0.f);
        if (OUTSLICED)
          ((unsigned short*)out)[((size_t)(col >> 5) * M + grow) * 32 + (col & 31)] =
              (unsigned short)f2bf(v);
        else
          ((float*)out)[(size_t)grow * ncols + col] = v;
      }
    }
  }
}

// ---------------------------------------------------------------------------
extern "C" void kernel_launch(void* const* d_in, const int* in_sizes, int n_in,
                              void* d_out, int out_size, void* d_ws, size_t ws_size,
                              hipStream_t stream) {
  const float* x   = (const float*)d_in[0];
  const int*   src = (const int*)d_in[1];
  const int*   dst = (const int*)d_in[2];
  const float* W0  = (const float*)d_in[3];
  const float* b0  = (const float*)d_in[4];
  const float* W1  = (const float*)d_in[5];
  const float* b1  = (const float*)d_in[6];
  const float* W2  = (const float*)d_in[7];
  const float* b2  = (const float*)d_in[8];
  float* out = (float*)d_out;

  const int M = in_sizes[0] / D;  // 50000 (divisible by 16)
  const int E = in_sizes[1];      // 600000

  // ws layout (16B-aligned chunks), feature buffers in SLICED layout:
  // [xb M*128 bf16][t M*128 bf16][hb M*128 bf16][W0b][W1b][W2b 48x128]
  // [counts M][row_start M+4][col_idx E][partials 64]
  char* p = (char*)d_ws;
  unsigned short* xb = (unsigned short*)p;  p += (size_t)M * D * 2;
  unsigned short* t  = (unsigned short*)p;  p += (size_t)M * D * 2;
  unsigned short* hb = (unsigned short*)p;  p += (size_t)M * D * 2;
  unsigned short* W0b = (unsigned short*)p;  p += 128 * 128 * 2;
  unsigned short* W1b = (unsigned short*)p;  p += 128 * 128 * 2;
  unsigned short* W2b = (unsigned short*)p;  p += 48 * 128 * 2;
  int* counts    = (int*)p;  p += (size_t)M * 4;
  int* row_start = (int*)p;  p += (size_t)(M + 4) * 4;
  int* col_idx   = (int*)p;  p += (size_t)E * 4;
  int* partials  = (int*)p;

  const int n4 = M / 4;
  const int scanBlocks = (n4 + 255) / 256;
  const int edgeBlocks = (E + 255) / 256;
  const int gatherBlocks = (M / 16) * 4;       // 4 passes, 16 nodes/block
  const int gemmBlocks = (M + 63) / 64;

  const int xConv4 = M * D / 4;
  const int nxb = (xConv4 + 255) / 256;
  const int nwb = (128 * 128 * 2 + 48 * 128 + 255) / 256;

  // --- CSR build ---
  hipMemsetAsync(counts, 0, (size_t)M * sizeof(int), stream);
  count_kernel<<<edgeBlocks, 256, 0, stream>>>(dst, counts, E);
  scan_partA<<<scanBlocks, 256, 0, stream>>>(counts, partials, n4);
  scan_partB<<<1, 64, 0, stream>>>(partials, row_start, scanBlocks, M, E);
  scan_partC<<<scanBlocks, 256, 0, stream>>>(counts, partials, row_start, n4);
  fill_kernel<<<edgeBlocks, 256, 0, stream>>>(src, dst, counts, col_idx, E);

  // --- Convert x (sliced) + weights to bf16 ---
  convert_all<<<nxb + nwb, 256, 0, stream>>>(
      (const float4*)x, (unsigned*)xb, xConv4, nxb, M, W0, W1, W2, W0b, W1b, W2b);

  // --- Layer 0 ---
  gather_sliced<<<gatherBlocks, 256, 0, stream>>>(
      (const unsigned*)xb, row_start, col_idx, (unsigned*)t, M);
  gemm_mfma<8, true, true><<<gemmBlocks, 256, 0, stream>>>(t, W0b, b0, hb, M, D);
  // --- Layer 1 ---
  gather_sliced<<<gatherBlocks, 256, 0, stream>>>(
      (const unsigned*)hb, row_start, col_idx, (unsigned*)t, M);
  gemm_mfma<8, true, true><<<gemmBlocks, 256, 0, stream>>>(t, W1b, b1, hb, M, D);
  // --- Layer 2 (fp32 out, no relu) ---
  gather_sliced<<<gatherBlocks, 256, 0, stream>>>(
      (const unsigned*)hb, row_start, col_idx, (unsigned*)t, M);
  gemm_mfma<3, false, false><<<gemmBlocks, 256, 0, stream>>>(t, W2b, b2, out, M, N_CLS);
}

// Round 7
// 299.474 us; speedup vs baseline: 1.1949x; 1.1949x over previous
//
#include <hip/hip_runtime.h>

#define D 128
#define N_CLS 40

// ---------------------------------------------------------------------------
// bf16 helpers (RNE)
// ---------------------------------------------------------------------------
__device__ __forceinline__ unsigned f2bf(float f) {
  unsigned u = __builtin_bit_cast(unsigned, f);
  u += 0x7fffu + ((u >> 16) & 1u);
  return u >> 16;
}
__device__ __forceinline__ float bf_lo(unsigned u) {
  return __builtin_bit_cast(float, u << 16);
}
__device__ __forceinline__ float bf_hi(unsigned u) {
  return __builtin_bit_cast(float, u & 0xffff0000u);
}

// ---------------------------------------------------------------------------
// CSR build step 1: counts[dst[e]]++
// ---------------------------------------------------------------------------
__global__ __launch_bounds__(256) void count_kernel(
    const int* __restrict__ dst, int* __restrict__ counts, int n_edges) {
  int e = blockIdx.x * 256 + threadIdx.x;
  if (e < n_edges) atomicAdd(&counts[dst[e]], 1);
}

// 3-phase device-wide exclusive scan over counts[n] (n % 4 == 0).
__global__ __launch_bounds__(256) void scan_partA(
    const int* __restrict__ counts, int* __restrict__ partials, int n4) {
  __shared__ int sh[256];
  const int tid = threadIdx.x;
  const int g = blockIdx.x * 256 + tid;
  int s = 0;
  if (g < n4) {
    const int4 c = reinterpret_cast<const int4*>(counts)[g];
    s = c.x + c.y + c.z + c.w;
  }
  sh[tid] = s;
  __syncthreads();
  for (int off = 128; off > 0; off >>= 1) {
    if (tid < off) sh[tid] += sh[tid + off];
    __syncthreads();
  }
  if (tid == 0) partials[blockIdx.x] = sh[0];
}

__global__ __launch_bounds__(64) void scan_partB(
    int* __restrict__ partials, int* __restrict__ row_start, int nP,
    int n, int n_edges) {
  const int lane = threadIdx.x;
  int v = (lane < nP) ? partials[lane] : 0;
  int x = v;
  for (int off = 1; off < 64; off <<= 1) {
    int y = __shfl_up(x, off, 64);
    if (lane >= off) x += y;
  }
  if (lane < nP) partials[lane] = x - v;
  if (lane == 0) row_start[n] = n_edges;
}

__global__ __launch_bounds__(256) void scan_partC(
    int* __restrict__ counts, const int* __restrict__ partials,
    int* __restrict__ row_start, int n4) {
  __shared__ int sh[256];
  const int tid = threadIdx.x;
  const int g = blockIdx.x * 256 + tid;
  int4 c = make_int4(0, 0, 0, 0);
  if (g < n4) c = reinterpret_cast<const int4*>(counts)[g];
  const int s0 = c.x;
  const int s1 = s0 + c.y;
  const int s2 = s1 + c.z;
  const int s3 = s2 + c.w;
  sh[tid] = s3;
  __syncthreads();
  for (int off = 1; off < 256; off <<= 1) {
    int y = (tid >= off) ? sh[tid - off] : 0;
    __syncthreads();
    sh[tid] += y;
    __syncthreads();
  }
  if (g < n4) {
    const int base = partials[blockIdx.x] + sh[tid] - s3;
    const int4 rs = make_int4(base, base + s0, base + s1, base + s2);
    reinterpret_cast<int4*>(row_start)[g] = rs;
    reinterpret_cast<int4*>(counts)[g] = rs;
  }
}

__global__ __launch_bounds__(256) void fill_kernel(
    const int* __restrict__ src, const int* __restrict__ dst,
    int* __restrict__ cursor, int* __restrict__ col_idx, int n_edges) {
  int e = blockIdx.x * 256 + threadIdx.x;
  if (e < n_edges) {
    int p = atomicAdd(&cursor[dst[e]], 1);
    col_idx[p] = src[e];
  }
}

// ---------------------------------------------------------------------------
// Merged converter: blocks [0, nxb) convert x (float4 -> 2x packed bf16),
// blocks [nxb, ...) convert W0/W1/W2 (W2 padded to 48 rows).
// ---------------------------------------------------------------------------
__global__ __launch_bounds__(256) void convert_all(
    const float4* __restrict__ x4, uint2* __restrict__ xb, int n4, int nxb,
    const float* __restrict__ W0, const float* __restrict__ W1,
    const float* __restrict__ W2, unsigned short* __restrict__ W0b,
    unsigned short* __restrict__ W1b, unsigned short* __restrict__ W2b) {
  if ((int)blockIdx.x < nxb) {
    int i = blockIdx.x * 256 + threadIdx.x;
    if (i < n4) {
      float4 v = x4[i];
      xb[i] = make_uint2(f2bf(v.x) | (f2bf(v.y) << 16),
                         f2bf(v.z) | (f2bf(v.w) << 16));
    }
  } else {
    int idx = (blockIdx.x - nxb) * 256 + threadIdx.x;
    const int n0 = 128 * 128, n1 = 128 * 128, n2 = 48 * 128;
    if (idx < n0) {
      W0b[idx] = (unsigned short)f2bf(W0[idx]);
    } else if (idx < n0 + n1) {
      int i = idx - n0;
      W1b[i] = (unsigned short)f2bf(W1[i]);
    } else if (idx < n0 + n1 + n2) {
      int i = idx - n0 - n1;
      int r = i >> 7;
      W2b[i] = (r < N_CLS) ? (unsigned short)f2bf(W2[i]) : (unsigned short)0;
    }
  }
}

// ---------------------------------------------------------------------------
// Gather-aggregate in bf16: out[n] = h[n] + sum_{j in row n} h[col_idx[j]]
// One wave per node (wave-uniform loop bounds -> col_idx on scalar path).
// 1 dword (2 bf16) per lane = 256 B/row per load instruction.
// Unroll-8: 8 independent row loads in flight + 8 accumulator pairs (MLP).
// fp32 accumulation; nontemporal store of the streamed output.
// ---------------------------------------------------------------------------
__global__ __launch_bounds__(256) void gather_bf16(
    const unsigned* __restrict__ h, const int* __restrict__ row_start,
    const int* __restrict__ col_idx, unsigned* __restrict__ out, int n_nodes) {
  int wave = (blockIdx.x * 256 + threadIdx.x) >> 6;
  int lane = threadIdx.x & 63;
  if (wave >= n_nodes) return;
  int s = row_start[wave];
  int e = row_start[wave + 1];
  unsigned su = h[(size_t)wave * 64 + lane];  // self term
  float ax[8], ay[8];
  ax[0] = bf_lo(su); ay[0] = bf_hi(su);
#pragma unroll
  for (int i = 1; i < 8; ++i) { ax[i] = 0.f; ay[i] = 0.f; }

  int j = s;
  for (; j + 7 < e; j += 8) {
    unsigned v[8];
#pragma unroll
    for (int i = 0; i < 8; ++i) {
      int u = col_idx[j + i];
      v[i] = h[(size_t)u * 64 + lane];
    }
#pragma unroll
    for (int i = 0; i < 8; ++i) { ax[i] += bf_lo(v[i]); ay[i] += bf_hi(v[i]); }
  }
  if (j + 3 < e) {
    unsigned v[4];
#pragma unroll
    for (int i = 0; i < 4; ++i) {
      int u = col_idx[j + i];
      v[i] = h[(size_t)u * 64 + lane];
    }
#pragma unroll
    for (int i = 0; i < 4; ++i) { ax[i] += bf_lo(v[i]); ay[i] += bf_hi(v[i]); }
    j += 4;
  }
  for (; j < e; ++j) {
    unsigned v = h[(size_t)col_idx[j] * 64 + lane];
    ax[0] += bf_lo(v); ay[0] += bf_hi(v);
  }

  float sx = (ax[0] + ax[1]) + (ax[2] + ax[3]) + ((ax[4] + ax[5]) + (ax[6] + ax[7]));
  float sy = (ay[0] + ay[1]) + (ay[2] + ay[3]) + ((ay[4] + ay[5]) + (ay[6] + ay[7]));
  __builtin_nontemporal_store(f2bf(sx) | (f2bf(sy) << 16),
                              out + (size_t)wave * 64 + lane);
}

// ---------------------------------------------------------------------------
// MFMA GEMM: out[M, ncols] = act(A[M,128] @ B[NT*16,128]^T + bias)
// A, B bf16 row-major (K=128 contiguous). Block = 256 thr = 4 waves, 64 rows.
// A/B-frag: lane holds row (lane&15), k = (lane>>4)*8 + j  (16 B loads).
// C/D: col = lane&15, row = (lane>>4)*4 + reg.
// ---------------------------------------------------------------------------
typedef __attribute__((ext_vector_type(8))) short bf16x8;
typedef __attribute__((ext_vector_type(4))) float f32x4;

template <int NT, bool RELU, bool OUTBF16>
__global__ __launch_bounds__(256) void gemm_mfma(
    const unsigned short* __restrict__ A, const unsigned short* __restrict__ B,
    const float* __restrict__ bias, void* __restrict__ out, int M, int ncols) {
  const int tid = threadIdx.x;
  const int wv = tid >> 6;
  const int lane = tid & 63;
  const int m_base = blockIdx.x * 64 + wv * 16;
  const int r16 = lane & 15;
  const int quad = lane >> 4;

  // A fragments for all 4 k-steps (rows may run past M; reads stay inside ws)
  const short* Ap = (const short*)A + (size_t)(m_base + r16) * D + quad * 8;
  bf16x8 af[4];
#pragma unroll
  for (int ks = 0; ks < 4; ++ks)
    af[ks] = *reinterpret_cast<const bf16x8*>(Ap + ks * 32);

  f32x4 acc[NT];
#pragma unroll
  for (int nt = 0; nt < NT; ++nt) {
    acc[nt] = (f32x4){0.f, 0.f, 0.f, 0.f};
    const short* Bp = (const short*)B + (size_t)(nt * 16 + r16) * D + quad * 8;
#pragma unroll
    for (int ks = 0; ks < 4; ++ks) {
      bf16x8 bf = *reinterpret_cast<const bf16x8*>(Bp + ks * 32);
      acc[nt] = __builtin_amdgcn_mfma_f32_16x16x32_bf16(af[ks], bf, acc[nt], 0, 0, 0);
    }
  }

  const int orow = m_base + quad * 4;
#pragma unroll
  for (int nt = 0; nt < NT; ++nt) {
    int col = nt * 16 + r16;
    float bv = (col < ncols) ? bias[col] : 0.f;
#pragma unroll
    for (int r = 0; r < 4; ++r) {
      int grow = orow + r;
      if (grow < M && col < ncols) {
        float v = acc[nt][r] + bv;
        if (RELU) v = fmaxf(v, 0.f);
        if (OUTBF16)
          ((unsigned short*)out)[(size_t)grow * D + col] = (unsigned short)f2bf(v);
        else
          ((float*)out)[(size_t)grow * ncols + col] = v;
      }
    }
  }
}

// ---------------------------------------------------------------------------
extern "C" void kernel_launch(void* const* d_in, const int* in_sizes, int n_in,
                              void* d_out, int out_size, void* d_ws, size_t ws_size,
                              hipStream_t stream) {
  const float* x   = (const float*)d_in[0];
  const int*   src = (const int*)d_in[1];
  const int*   dst = (const int*)d_in[2];
  const float* W0  = (const float*)d_in[3];
  const float* b0  = (const float*)d_in[4];
  const float* W1  = (const float*)d_in[5];
  const float* b1  = (const float*)d_in[6];
  const float* W2  = (const float*)d_in[7];
  const float* b2  = (const float*)d_in[8];
  float* out = (float*)d_out;

  const int M = in_sizes[0] / D;  // 50000
  const int E = in_sizes[1];      // 600000

  // ws layout (16B-aligned chunks):
  // [xb bf16 M*128][t bf16 M*128][hb bf16 M*128][W0b][W1b][W2b 48x128]
  // [counts M][row_start M+4][col_idx E][partials 64]
  char* p = (char*)d_ws;
  unsigned short* xb = (unsigned short*)p;  p += (size_t)M * D * 2;
  unsigned short* t  = (unsigned short*)p;  p += (size_t)M * D * 2;
  unsigned short* hb = (unsigned short*)p;  p += (size_t)M * D * 2;
  unsigned short* W0b = (unsigned short*)p;  p += 128 * 128 * 2;
  unsigned short* W1b = (unsigned short*)p;  p += 128 * 128 * 2;
  unsigned short* W2b = (unsigned short*)p;  p += 48 * 128 * 2;
  int* counts    = (int*)p;  p += (size_t)M * 4;
  int* row_start = (int*)p;  p += (size_t)(M + 4) * 4;
  int* col_idx   = (int*)p;  p += (size_t)E * 4;
  int* partials  = (int*)p;

  const int n4 = M / 4;
  const int scanBlocks = (n4 + 255) / 256;
  const int edgeBlocks = (E + 255) / 256;
  const int gatherBlocks = (M * 64 + 255) / 256;  // 1 wave per node
  const int gemmBlocks = (M + 63) / 64;

  const int xConv4 = M * D / 4;
  const int nxb = (xConv4 + 255) / 256;
  const int nwb = (128 * 128 * 2 + 48 * 128 + 255) / 256;

  // --- CSR build ---
  hipMemsetAsync(counts, 0, (size_t)M * sizeof(int), stream);
  count_kernel<<<edgeBlocks, 256, 0, stream>>>(dst, counts, E);
  scan_partA<<<scanBlocks, 256, 0, stream>>>(counts, partials, n4);
  scan_partB<<<1, 64, 0, stream>>>(partials, row_start, scanBlocks, M, E);
  scan_partC<<<scanBlocks, 256, 0, stream>>>(counts, partials, row_start, n4);
  fill_kernel<<<edgeBlocks, 256, 0, stream>>>(src, dst, counts, col_idx, E);

  // --- Convert x + weights to bf16 ---
  convert_all<<<nxb + nwb, 256, 0, stream>>>(
      (const float4*)x, (uint2*)xb, xConv4, nxb, W0, W1, W2, W0b, W1b, W2b);

  // --- Layer 0 ---
  gather_bf16<<<gatherBlocks, 256, 0, stream>>>(
      (const unsigned*)xb, row_start, col_idx, (unsigned*)t, M);
  gemm_mfma<8, true, true><<<gemmBlocks, 256, 0, stream>>>(t, W0b, b0, hb, M, D);
  // --- Layer 1 ---
  gather_bf16<<<gatherBlocks, 256, 0, stream>>>(
      (const unsigned*)hb, row_start, col_idx, (unsigned*)t, M);
  gemm_mfma<8, true, true><<<gemmBlocks, 256, 0, stream>>>(t, W1b, b1, hb, M, D);
  // --- Layer 2 (fp32 out, no relu) ---
  gather_bf16<<<gatherBlocks, 256, 0, stream>>>(
      (const unsigned*)hb, row_start, col_idx, (unsigned*)t, M);
  gemm_mfma<3, false, false><<<gemmBlocks, 256, 0, stream>>>(t, W2b, b2, out, M, N_CLS);
}